// Round 2
// baseline (1454.868 us; speedup 1.0000x reference)
//
#include <hip/hip_runtime.h>

// DeepAR forward: B=32, L_IN=336, L_OUT=48, N=512, COV=4, EMB=32, H=64
// T = 383 steps, BN = 16384 sequences. 32 seqs per WG, 512 WGs, persistent.
//
// R4: cross-layer software pipeline. Back to 256 thr/WG (4 waves, wave=jt
// owns both mt seq-tiles; 8 waves/CU, VGPR budget 256 — R3's 16-wave regime
// spilled 340 MB to scratch for zero gain since the kernel is issue-bound).
// Each phase p computes L0(t=p) AND L1(t=p-1) in the same wave:
//   read-half : all LDS reads (h0(p-1) shared by L0+L1, h1(p-2), x(p), W1)
//               + both MFMA blocks + both epilogues + head(p-2)
//   MID barrier
//   write-half: store h0(p), h1(p-1), stage x(p+1), prefetch x(p+2)
//   END barrier
// 2 barriers/phase replace R2's 4/step; L0's trans-heavy epilogue overlaps
// L1's MFMA+DS within the wave (separate pipes). Swapped-operand MFMA kept
// (W as A-op): lane owns 4 consecutive hidden units of one seq -> b64 h-store.
// L0 bias folded into constant-1.0 columns 133/134; L1 bias f32 in regs.

#define N_PHASES 385   // p=0..384: L0 t=p (p<=382), L1 t=p-1 (1<=p<=383), head t=p-2 (p>=337)
#define AST 168        // A row stride in shorts: [h0 0..63 | h1 64..127 | in 128..132 | 1.0 @133,134 | pad]

typedef __attribute__((ext_vector_type(8))) short short8;
typedef __attribute__((ext_vector_type(4))) short s16x4;
typedef __attribute__((ext_vector_type(4))) float floatx4;

__device__ __forceinline__ unsigned short f2bf(float f){   // RNE (prologue)
  union { float f; unsigned u; } v; v.f = f;
  unsigned u = v.u + 0x7fffu + ((v.u >> 16) & 1u);
  return (unsigned short)(u >> 16);
}
__device__ __forceinline__ unsigned short f2bf_fast(float f){  // round-half-up, 2 instrs
  union { float f; unsigned u; } v; v.f = f;
  return (unsigned short)((v.u + 0x8000u) >> 16);
}
__device__ __forceinline__ float bf2f(unsigned short b){
  union { unsigned u; float f; } v; v.u = ((unsigned)b) << 16; return v.f;
}
__device__ __forceinline__ float fsig(float x){
  return __builtin_amdgcn_rcpf(1.f + __expf(-x));
}
__device__ __forceinline__ float ftanh(float x){
  return 1.f - 2.f * __builtin_amdgcn_rcpf(1.f + __expf(2.f * x));
}

__global__ __launch_bounds__(256, 2) void deepar_kernel(
    const float* __restrict__ hist, const float* __restrict__ fut,
    const float* __restrict__ embW, const float* __restrict__ embB,
    const float* __restrict__ Wih0, const float* __restrict__ Whh0,
    const float* __restrict__ bih0, const float* __restrict__ bhh0,
    const float* __restrict__ Wih1, const float* __restrict__ Whh1,
    const float* __restrict__ bih1, const float* __restrict__ bhh1,
    const float* __restrict__ headW, const float* __restrict__ headB,
    float* __restrict__ outp)
{
  const int tid  = threadIdx.x;
  const int lane = tid & 63;
  const int wv   = tid >> 6;        // 0..3 == jt (hidden 16-block)
  const int l15  = lane & 15;
  const int quad = lane >> 4;       // 0..3
  const int koff = quad * 8;
  const int jt   = wv;
  const int jbase = jt * 16 + quad * 4;  // first of this lane's 4 hidden units

  const int b  = blockIdx.x >> 4;            // batch
  const int n0 = (blockIdx.x & 15) * 32;     // first series index

  __shared__ __align__(16) unsigned short A[32 * AST];
  __shared__ __align__(16) unsigned short W1[64 * 64 * 8];  // 64 frags x 64 lanes x 8 bf16
  __shared__ float HW[128];

  for (int i = tid; i < 32 * AST; i += 256) A[i] = 0;
  if (tid < 128) HW[tid] = headW[tid];
  __syncthreads();   // zero-fill complete before constant/input writes
  if (tid < 32){
    A[tid * AST + 133] = 0x3f80;   // 1.0 (bias-hi column)
    A[tid * AST + 134] = 0x3f80;   // 1.0 (bias-residual column)
  }
  const float hb0 = headB[0], hb1 = headB[1];

  // ---- layer-0 weight A-frags in registers; layer-1 A-frags -> LDS ----
  // A-frag (16x16x32): lane holds A[row = lane&15][k = quad*8 + j], j=0..7
  short8 bf0[4][3];   // [gate][kf]: kf0,1 = Whh0 (k 0..63); kf2 = input cols (k 128..159)
  floatx4 bi1v[4];    // layer-1 bias for this lane's 4 hidden units, per gate
  #pragma unroll
  for (int g = 0; g < 4; ++g){
    const int rf = g * 64 + jt * 16 + l15;     // frag row (gate row)
    float u = 0.f, bb = bih0[rf] + bhh0[rf];
    #pragma unroll
    for (int e = 0; e < 32; ++e){
      float wval = Wih0[rf * 36 + e];
      u  += wval * embW[e];
      bb += wval * embB[e];
    }
    const unsigned short bbq = f2bf(bb);       // bias hi (bf16)
    const float bbr = bb - bf2f(bbq);          // bias residual
    #pragma unroll
    for (int kf = 0; kf < 2; ++kf)
      #pragma unroll
      for (int j = 0; j < 8; ++j)
        bf0[g][kf][j] = (short)f2bf(Whh0[rf * 64 + kf * 32 + koff + j]);
    #pragma unroll
    for (int j = 0; j < 8; ++j){
      const int kk = koff + j;    // local k within input frag; col = 128+kk
      float v = 0.f;
      if (kk == 0) v = u;                                   // prev -> u[rf]
      else if (kk >= 1 && kk <= 4) v = Wih0[rf * 36 + 32 + (kk - 1)];
      else if (kk == 6) v = bbr;                            // residual * 1.0
      unsigned short q16 = (kk == 5) ? bbq : f2bf(v);       // hi * 1.0
      bf0[g][2][j] = (short)q16;
    }
    #pragma unroll
    for (int q = 0; q < 4; ++q){
      const int re = g * 64 + jt * 16 + quad * 4 + q;  // epilogue row (this lane's j)
      bi1v[g][q] = bih1[re] + bhh1[re];
    }
    // every wave owns a unique jt: fill its 16 W1 frags
    #pragma unroll
    for (int kf = 0; kf < 4; ++kf){
      const float* src = (kf < 2) ? (Wih1 + rf * 64 + kf * 32)
                                  : (Whh1 + rf * 64 + (kf - 2) * 32);
      short8 w;
      #pragma unroll
      for (int j = 0; j < 8; ++j)
        w[j] = (short)f2bf(src[koff + j]);
      *(short8*)&W1[((jt * 16 + g * 4 + kf) * 64 + lane) * 8] = w;
    }
  }

  // ---- input staging (prev: 32 threads; cov: 128 threads) ----
  const bool isPrev = (tid < 32);
  const bool isCov  = (tid >= 64 && tid < 192);
  int ss = 0, cc = 0;
  if (isPrev){ ss = tid; cc = 0; }
  if (isCov) { ss = (tid - 64) >> 2; cc = 1 + ((tid - 64) & 3); }
  const int myN = n0 + ss;

  auto loadSlab = [&](int tt) -> float {
    if (isPrev){
      int l = tt; if (l > 383) l = 383;
      return (l < 336) ? hist[(((size_t)b * 336 + l) * 512 + myN) * 5]
                       : fut [(((size_t)b * 48 + (l - 336)) * 512 + myN) * 5];
    } else if (isCov){
      int l = tt + 1; if (l > 383) l = 383;
      return (l < 336) ? hist[(((size_t)b * 336 + l) * 512 + myN) * 5 + cc]
                       : fut [(((size_t)b * 48 + (l - 336)) * 512 + myN) * 5 + cc];
    }
    return 0.f;
  };

  float rIn = loadSlab(0);
  if (isPrev || isCov) A[ss * AST + 128 + cc] = f2bf(rIn);
  rIn = loadSlab(1);   // rIn holds x(p+1) entering each phase's write-half

  float c0s[8], c1s[8];
  #pragma unroll
  for (int i = 0; i < 8; ++i){ c0s[i] = 0.f; c1s[i] = 0.f; }

  __syncthreads();

  for (int p = 0; p < N_PHASES; ++p){
    const bool doL0 = (p <= 382);
    const bool doL1 = (p >= 1 && p <= 383);

    // ---------- READ-HALF: all shared-state reads + compute ----------
    short8 xh0[2][2], xh1[2][2], xin[2];
    #pragma unroll
    for (int mt = 0; mt < 2; ++mt){
      const int rbase = (mt * 16 + l15) * AST;
      xh0[mt][0] = *(const short8*)&A[rbase +  0 + koff];   // h0(p-1) k 0..31
      xh0[mt][1] = *(const short8*)&A[rbase + 32 + koff];   // h0(p-1) k 32..63
      xh1[mt][0] = *(const short8*)&A[rbase + 64 + koff];   // h1(p-2) k 0..31
      xh1[mt][1] = *(const short8*)&A[rbase + 96 + koff];   // h1(p-2) k 32..63
      xin[mt]    = *(const short8*)&A[rbase + 128 + koff];  // x(p) + bias cols
    }

    floatx4 acc0[4][2], acc1[4][2];
    #pragma unroll
    for (int g = 0; g < 4; ++g)
      #pragma unroll
      for (int mt = 0; mt < 2; ++mt){
        floatx4 z = {0.f, 0.f, 0.f, 0.f};
        acc0[g][mt] = z;
        acc1[g][mt] = bi1v[g];
      }

    if (doL0){   // L0(t=p): consumes h0(p-1), x(p)
      #pragma unroll
      for (int mt = 0; mt < 2; ++mt)
        #pragma unroll
        for (int g = 0; g < 4; ++g){
          acc0[g][mt] = __builtin_amdgcn_mfma_f32_16x16x32_bf16(bf0[g][0], xh0[mt][0], acc0[g][mt], 0, 0, 0);
          acc0[g][mt] = __builtin_amdgcn_mfma_f32_16x16x32_bf16(bf0[g][1], xh0[mt][1], acc0[g][mt], 0, 0, 0);
          acc0[g][mt] = __builtin_amdgcn_mfma_f32_16x16x32_bf16(bf0[g][2], xin[mt],   acc0[g][mt], 0, 0, 0);
        }
    }
    if (doL1){   // L1(t=p-1): consumes h0(p-1) (shared reads!), h1(p-2)
      #pragma unroll
      for (int kf = 0; kf < 4; ++kf){
        const short8 w0 = *(const short8*)&W1[((jt * 16 +  0 + kf) * 64 + lane) * 8];
        const short8 w1 = *(const short8*)&W1[((jt * 16 +  4 + kf) * 64 + lane) * 8];
        const short8 w2 = *(const short8*)&W1[((jt * 16 +  8 + kf) * 64 + lane) * 8];
        const short8 w3 = *(const short8*)&W1[((jt * 16 + 12 + kf) * 64 + lane) * 8];
        #pragma unroll
        for (int mt = 0; mt < 2; ++mt){
          const short8 xf = (kf < 2) ? xh0[mt][kf] : xh1[mt][kf - 2];
          acc1[0][mt] = __builtin_amdgcn_mfma_f32_16x16x32_bf16(w0, xf, acc1[0][mt], 0, 0, 0);
          acc1[1][mt] = __builtin_amdgcn_mfma_f32_16x16x32_bf16(w1, xf, acc1[1][mt], 0, 0, 0);
          acc1[2][mt] = __builtin_amdgcn_mfma_f32_16x16x32_bf16(w2, xf, acc1[2][mt], 0, 0, 0);
          acc1[3][mt] = __builtin_amdgcn_mfma_f32_16x16x32_bf16(w3, xf, acc1[3][mt], 0, 0, 0);
        }
      }
    }

    float hn0[8], hn1[8];
    if (doL0){
      #pragma unroll
      for (int mt = 0; mt < 2; ++mt)
        #pragma unroll
        for (int q = 0; q < 4; ++q){
          const int idx = mt * 4 + q;
          float iv = acc0[0][mt][q], fv = acc0[1][mt][q];
          float gv = acc0[2][mt][q], ov = acc0[3][mt][q];
          float c = fsig(fv) * c0s[idx] + fsig(iv) * ftanh(gv);
          c0s[idx] = c;
          hn0[idx] = fsig(ov) * ftanh(c);
        }
    }
    if (doL1){
      #pragma unroll
      for (int mt = 0; mt < 2; ++mt)
        #pragma unroll
        for (int q = 0; q < 4; ++q){
          const int idx = mt * 4 + q;
          float iv = acc1[0][mt][q], fv = acc1[1][mt][q];
          float gv = acc1[2][mt][q], ov = acc1[3][mt][q];
          float c = fsig(fv) * c1s[idx] + fsig(iv) * ftanh(gv);
          c1s[idx] = c;
          hn1[idx] = fsig(ov) * ftanh(c);
        }
    }

    // head(t' = p-2): reads h1(p-2) still resident in A (overwritten only
    // in the coming write-half, which writes h1(p-1)).
    if (p >= 337){
      const int hs = tid >> 3, outc = (tid >> 2) & 1, part = tid & 3;
      const short8 hv0 = *(const short8*)&A[hs * AST + 64 + part * 16];
      const short8 hv1 = *(const short8*)&A[hs * AST + 64 + part * 16 + 8];
      float pv = 0.f;
      #pragma unroll
      for (int jj = 0; jj < 8; ++jj){
        float a0 = fmaxf(bf2f((unsigned short)hv0[jj]), 0.f);
        float a1 = fmaxf(bf2f((unsigned short)hv1[jj]), 0.f);
        pv += a0 * HW[outc * 64 + part * 16 + jj];
        pv += a1 * HW[outc * 64 + part * 16 + 8 + jj];
      }
      pv += __shfl_xor(pv, 1);
      pv += __shfl_xor(pv, 2);
      if ((tid & 3) == 0){
        float val;
        if (outc == 0) val = pv + hb0;
        else {
          float x = pv + hb1;   // softplus, stable
          val = fmaxf(x, 0.f) + __logf(1.f + __expf(-fabsf(x)));
        }
        outp[(((size_t)b * 48 + (p - 337)) * 512 + (n0 + hs)) * 2 + outc] = val;
      }
    }

    __syncthreads();   // MID: all reads of shared state done

    // ---------- WRITE-HALF: publish h0(p), h1(p-1), x(p+1) ----------
    if (doL0){
      #pragma unroll
      for (int mt = 0; mt < 2; ++mt){
        s16x4 pk;
        #pragma unroll
        for (int q = 0; q < 4; ++q) pk[q] = (short)f2bf_fast(hn0[mt * 4 + q]);
        *(s16x4*)&A[(mt * 16 + l15) * AST + jbase] = pk;        // h0(p)
      }
    }
    if (doL1){
      #pragma unroll
      for (int mt = 0; mt < 2; ++mt){
        s16x4 pk;
        #pragma unroll
        for (int q = 0; q < 4; ++q) pk[q] = (short)f2bf_fast(hn1[mt * 4 + q]);
        *(s16x4*)&A[(mt * 16 + l15) * AST + 64 + jbase] = pk;   // h1(p-1)
      }
    }
    if (isPrev || isCov) A[ss * AST + 128 + cc] = f2bf_fast(rIn);  // x(p+1)
    rIn = loadSlab(p + 2);                                          // prefetch x(p+2)

    __syncthreads();   // END: next phase may read
  }
}

extern "C" void kernel_launch(void* const* d_in, const int* in_sizes, int n_in,
                              void* d_out, int out_size, void* d_ws, size_t ws_size,
                              hipStream_t stream) {
  (void)in_sizes; (void)n_in; (void)out_size; (void)d_ws; (void)ws_size;
  deepar_kernel<<<dim3(512), dim3(256), 0, stream>>>(
      (const float*)d_in[0],  (const float*)d_in[1],
      (const float*)d_in[2],  (const float*)d_in[3],
      (const float*)d_in[4],  (const float*)d_in[5],
      (const float*)d_in[6],  (const float*)d_in[7],
      (const float*)d_in[8],  (const float*)d_in[9],
      (const float*)d_in[10], (const float*)d_in[11],
      (const float*)d_in[12], (const float*)d_in[13],
      (float*)d_out);
}

// Round 3
// 1379.892 us; speedup vs baseline: 1.0543x; 1.0543x over previous
//
#include <hip/hip_runtime.h>

// DeepAR forward: B=32, L_IN=336, L_OUT=48, N=512, COV=4, EMB=32, H=64
// T = 383 steps, BN = 16384 sequences. 32 seqs per WG, 512 WGs, persistent.
//
// R5: W1 in registers + double-buffered state, layer-sequential (R2 order).
//  - R3 lesson: occupancy is NOT the lever (issue-bound); stay at 2 waves/SIMD,
//    VGPR budget 256. R4 lesson: never hold two layers' acc live at once.
//  - W1 frags (16 x short8 = 64 VGPR) live in registers: removes 16 of 30
//    ds_read_b128 per wave-step (~50% of CU LDS-pipe load) and 64 KB LDS.
//  - A state double-buffered (2 x 32 x AST shorts = 21.5 KB): every store
//    targets the next-phase buffer, so h0/h1/x writes issue immediately
//    after the epilogue (no anti-dep wait); exactly 2 barriers/step:
//      L0 reads cur -> epi -> h0(t)->nxt, x(t+1)->nxt, head(t-1) from cur
//      B1 (h0 visible)
//      L1 reads h0(t) from nxt + h1(t-1) from cur -> epi -> h1(t)->nxt
//      B2 (h1, x visible; next phase swaps buffers)
//  - Swapped-operand MFMA kept (W as A-op): lane owns 4 consecutive hidden
//    units of one seq -> b64 h-store. L0 bias via constant-1.0 cols 133/134.

#define AST  168        // A row stride in shorts: [h0 0..63 | h1 64..127 | in 128..132 | 1.0 @133,134 | pad]
#define ABUF (32 * AST) // shorts per buffer

typedef __attribute__((ext_vector_type(8))) short short8;
typedef __attribute__((ext_vector_type(4))) short s16x4;
typedef __attribute__((ext_vector_type(4))) float floatx4;

__device__ __forceinline__ unsigned short f2bf(float f){   // RNE (prologue)
  union { float f; unsigned u; } v; v.f = f;
  unsigned u = v.u + 0x7fffu + ((v.u >> 16) & 1u);
  return (unsigned short)(u >> 16);
}
__device__ __forceinline__ unsigned short f2bf_fast(float f){  // round-half-up, 2 instrs
  union { float f; unsigned u; } v; v.f = f;
  return (unsigned short)((v.u + 0x8000u) >> 16);
}
__device__ __forceinline__ float bf2f(unsigned short b){
  union { unsigned u; float f; } v; v.u = ((unsigned)b) << 16; return v.f;
}
__device__ __forceinline__ float fsig(float x){
  return __builtin_amdgcn_rcpf(1.f + __expf(-x));
}
__device__ __forceinline__ float ftanh(float x){
  return 1.f - 2.f * __builtin_amdgcn_rcpf(1.f + __expf(2.f * x));
}

__global__ __launch_bounds__(256, 2) void deepar_kernel(
    const float* __restrict__ hist, const float* __restrict__ fut,
    const float* __restrict__ embW, const float* __restrict__ embB,
    const float* __restrict__ Wih0, const float* __restrict__ Whh0,
    const float* __restrict__ bih0, const float* __restrict__ bhh0,
    const float* __restrict__ Wih1, const float* __restrict__ Whh1,
    const float* __restrict__ bih1, const float* __restrict__ bhh1,
    const float* __restrict__ headW, const float* __restrict__ headB,
    float* __restrict__ outp)
{
  const int tid  = threadIdx.x;
  const int lane = tid & 63;
  const int wv   = tid >> 6;        // 0..3 == jt (hidden 16-block)
  const int l15  = lane & 15;
  const int quad = lane >> 4;       // 0..3
  const int koff = quad * 8;
  const int jt   = wv;
  const int jbase = jt * 16 + quad * 4;  // first of this lane's 4 hidden units

  const int b  = blockIdx.x >> 4;            // batch
  const int n0 = (blockIdx.x & 15) * 32;     // first series index

  __shared__ __align__(16) unsigned short A[2 * ABUF];
  __shared__ float HW[128];

  for (int i = tid; i < 2 * ABUF; i += 256) A[i] = 0;
  if (tid < 128) HW[tid] = headW[tid];
  __syncthreads();   // zero-fill complete before constant/input writes
  if (tid < 32){
    A[tid * AST + 133]        = 0x3f80;   // 1.0 bias-hi col, buf0
    A[tid * AST + 134]        = 0x3f80;   // 1.0 bias-residual col, buf0
    A[ABUF + tid * AST + 133] = 0x3f80;   // buf1
    A[ABUF + tid * AST + 134] = 0x3f80;
  }
  const float hb0 = headB[0], hb1 = headB[1];

  // ---- layer-0 AND layer-1 weight A-frags in registers ----
  // A-frag (16x16x32): lane holds A[row = lane&15][k = quad*8 + j], j=0..7
  short8 bf0[4][3];   // [gate][kf]: kf0,1 = Whh0 (k 0..63); kf2 = input cols (k 128..159)
  short8 w1f[4][4];   // [gate][kf]: kf0,1 = Wih1 (vs h0); kf2,3 = Whh1 (vs h1)
  floatx4 bi1v[4];    // layer-1 bias for this lane's 4 hidden units, per gate
  #pragma unroll
  for (int g = 0; g < 4; ++g){
    const int rf = g * 64 + jt * 16 + l15;     // frag row (gate row)
    float u = 0.f, bb = bih0[rf] + bhh0[rf];
    #pragma unroll
    for (int e = 0; e < 32; ++e){
      float wval = Wih0[rf * 36 + e];
      u  += wval * embW[e];
      bb += wval * embB[e];
    }
    const unsigned short bbq = f2bf(bb);       // bias hi (bf16)
    const float bbr = bb - bf2f(bbq);          // bias residual
    #pragma unroll
    for (int kf = 0; kf < 2; ++kf)
      #pragma unroll
      for (int j = 0; j < 8; ++j)
        bf0[g][kf][j] = (short)f2bf(Whh0[rf * 64 + kf * 32 + koff + j]);
    #pragma unroll
    for (int j = 0; j < 8; ++j){
      const int kk = koff + j;    // local k within input frag; col = 128+kk
      float v = 0.f;
      if (kk == 0) v = u;                                   // prev -> u[rf]
      else if (kk >= 1 && kk <= 4) v = Wih0[rf * 36 + 32 + (kk - 1)];
      else if (kk == 6) v = bbr;                            // residual * 1.0
      unsigned short q16 = (kk == 5) ? bbq : f2bf(v);       // hi * 1.0
      bf0[g][2][j] = (short)q16;
    }
    #pragma unroll
    for (int kf = 0; kf < 4; ++kf){
      const float* src = (kf < 2) ? (Wih1 + rf * 64 + kf * 32)
                                  : (Whh1 + rf * 64 + (kf - 2) * 32);
      #pragma unroll
      for (int j = 0; j < 8; ++j)
        w1f[g][kf][j] = (short)f2bf(src[koff + j]);
    }
    #pragma unroll
    for (int q = 0; q < 4; ++q){
      const int re = g * 64 + jt * 16 + quad * 4 + q;  // epilogue row (this lane's j)
      bi1v[g][q] = bih1[re] + bhh1[re];
    }
  }

  // ---- input staging (prev: 32 threads; cov: 128 threads) ----
  const bool isPrev = (tid < 32);
  const bool isCov  = (tid >= 64 && tid < 192);
  int ss = 0, cc = 0;
  if (isPrev){ ss = tid; cc = 0; }
  if (isCov) { ss = (tid - 64) >> 2; cc = 1 + ((tid - 64) & 3); }
  const int myN = n0 + ss;
  const int sb  = ss * AST + 128 + cc;    // staging write base (shorts, within buffer)

  auto loadSlab = [&](int tt) -> float {
    if (isPrev){
      int l = tt; if (l > 383) l = 383;
      return (l < 336) ? hist[(((size_t)b * 336 + l) * 512 + myN) * 5]
                       : fut [(((size_t)b * 48 + (l - 336)) * 512 + myN) * 5];
    } else if (isCov){
      int l = tt + 1; if (l > 383) l = 383;
      return (l < 336) ? hist[(((size_t)b * 336 + l) * 512 + myN) * 5 + cc]
                       : fut [(((size_t)b * 48 + (l - 336)) * 512 + myN) * 5 + cc];
    }
    return 0.f;
  };

  float rIn = loadSlab(0);
  if (isPrev || isCov) A[sb] = f2bf(rIn);   // x(0) -> buf0
  rIn = loadSlab(1);                         // rIn holds x(t+1) entering each phase

  float c0s[8], c1s[8];
  #pragma unroll
  for (int i = 0; i < 8; ++i){ c0s[i] = 0.f; c1s[i] = 0.f; }

  // per-lane bases (shorts, within buffer)
  const int r0 = l15 * AST;          // seq-tile mt=0 row
  const int r1 = r0 + 16 * AST;      // seq-tile mt=1 row
  const int hd_hs   = tid >> 3;                 // head: seq row
  const int hd_outc = (tid >> 2) & 1;           // head: output column
  const int hd_part = tid & 3;                  // head: 16-wide slice
  const int hd_base = hd_hs * AST + 64 + hd_part * 16;

  __syncthreads();

  auto headOp = [&](int tt, int co){   // reads h1(tt) from buffer co
    const short8 hv0 = *(const short8*)&A[co + hd_base];
    const short8 hv1 = *(const short8*)&A[co + hd_base + 8];
    float pv = 0.f;
    #pragma unroll
    for (int jj = 0; jj < 8; ++jj){
      float a0 = fmaxf(bf2f((unsigned short)hv0[jj]), 0.f);
      float a1 = fmaxf(bf2f((unsigned short)hv1[jj]), 0.f);
      pv += a0 * HW[hd_outc * 64 + hd_part * 16 + jj];
      pv += a1 * HW[hd_outc * 64 + hd_part * 16 + 8 + jj];
    }
    pv += __shfl_xor(pv, 1);
    pv += __shfl_xor(pv, 2);
    if ((tid & 3) == 0){
      float val;
      if (hd_outc == 0) val = pv + hb0;
      else {
        float x = pv + hb1;   // softplus, stable
        val = fmaxf(x, 0.f) + __logf(1.f + __expf(-fabsf(x)));
      }
      outp[(((size_t)b * 48 + (tt - 335)) * 512 + (n0 + hd_hs)) * 2 + hd_outc] = val;
    }
  };

  auto phase = [&](int t, int co, int no){
    // ===== layer 0: reads cur{h0(t-1), x(t)}; writes h0(t) -> nxt =====
    {
      short8 xh[2][2], xin[2];
      xh[0][0] = *(const short8*)&A[co + r0 + koff];
      xh[0][1] = *(const short8*)&A[co + r0 + 32 + koff];
      xin[0]   = *(const short8*)&A[co + r0 + 128 + koff];
      xh[1][0] = *(const short8*)&A[co + r1 + koff];
      xh[1][1] = *(const short8*)&A[co + r1 + 32 + koff];
      xin[1]   = *(const short8*)&A[co + r1 + 128 + koff];

      floatx4 acc[4][2];
      #pragma unroll
      for (int g = 0; g < 4; ++g)
        #pragma unroll
        for (int mt = 0; mt < 2; ++mt){
          floatx4 z = {0.f, 0.f, 0.f, 0.f};
          acc[g][mt] = z;
        }
      #pragma unroll
      for (int mt = 0; mt < 2; ++mt)
        #pragma unroll
        for (int g = 0; g < 4; ++g){
          acc[g][mt] = __builtin_amdgcn_mfma_f32_16x16x32_bf16(bf0[g][0], xh[mt][0], acc[g][mt], 0, 0, 0);
          acc[g][mt] = __builtin_amdgcn_mfma_f32_16x16x32_bf16(bf0[g][1], xh[mt][1], acc[g][mt], 0, 0, 0);
          acc[g][mt] = __builtin_amdgcn_mfma_f32_16x16x32_bf16(bf0[g][2], xin[mt],   acc[g][mt], 0, 0, 0);
        }
      #pragma unroll
      for (int mt = 0; mt < 2; ++mt){
        s16x4 pk;
        #pragma unroll
        for (int q = 0; q < 4; ++q){
          const int idx = mt * 4 + q;
          float iv = acc[0][mt][q], fv = acc[1][mt][q];
          float gv = acc[2][mt][q], ov = acc[3][mt][q];
          float c = fsig(fv) * c0s[idx] + fsig(iv) * ftanh(gv);
          c0s[idx] = c;
          pk[q] = (short)f2bf_fast(fsig(ov) * ftanh(c));
        }
        *(s16x4*)&A[no + (mt ? r1 : r0) + jbase] = pk;   // h0(t) -> nxt
      }
    }
    // stage x(t+1) -> nxt; prefetch x(t+2)
    if (isPrev || isCov) A[no + sb] = f2bf_fast(rIn);
    rIn = loadSlab(t + 2);
    // head(t-1) from cur h1 (stable this phase; nxt h1 written after B1)
    if (t >= 336) headOp(t - 1, co);

    __syncthreads();   // B1: h0(t) visible in nxt

    // ===== layer 1: reads nxt h0(t) + cur h1(t-1); writes h1(t) -> nxt =====
    {
      short8 y0[2][2], y1[2][2];
      y0[0][0] = *(const short8*)&A[no + r0 + koff];
      y0[0][1] = *(const short8*)&A[no + r0 + 32 + koff];
      y1[0][0] = *(const short8*)&A[co + r0 + 64 + koff];
      y1[0][1] = *(const short8*)&A[co + r0 + 96 + koff];
      y0[1][0] = *(const short8*)&A[no + r1 + koff];
      y0[1][1] = *(const short8*)&A[no + r1 + 32 + koff];
      y1[1][0] = *(const short8*)&A[co + r1 + 64 + koff];
      y1[1][1] = *(const short8*)&A[co + r1 + 96 + koff];

      floatx4 acc[4][2];
      #pragma unroll
      for (int g = 0; g < 4; ++g)
        #pragma unroll
        for (int mt = 0; mt < 2; ++mt)
          acc[g][mt] = bi1v[g];
      #pragma unroll
      for (int kf = 0; kf < 4; ++kf)
        #pragma unroll
        for (int mt = 0; mt < 2; ++mt){
          const short8 xf = (kf < 2) ? y0[mt][kf] : y1[mt][kf - 2];
          acc[0][mt] = __builtin_amdgcn_mfma_f32_16x16x32_bf16(w1f[0][kf], xf, acc[0][mt], 0, 0, 0);
          acc[1][mt] = __builtin_amdgcn_mfma_f32_16x16x32_bf16(w1f[1][kf], xf, acc[1][mt], 0, 0, 0);
          acc[2][mt] = __builtin_amdgcn_mfma_f32_16x16x32_bf16(w1f[2][kf], xf, acc[2][mt], 0, 0, 0);
          acc[3][mt] = __builtin_amdgcn_mfma_f32_16x16x32_bf16(w1f[3][kf], xf, acc[3][mt], 0, 0, 0);
        }
      #pragma unroll
      for (int mt = 0; mt < 2; ++mt){
        s16x4 pk;
        #pragma unroll
        for (int q = 0; q < 4; ++q){
          const int idx = mt * 4 + q;
          float iv = acc[0][mt][q], fv = acc[1][mt][q];
          float gv = acc[2][mt][q], ov = acc[3][mt][q];
          float c = fsig(fv) * c1s[idx] + fsig(iv) * ftanh(gv);
          c1s[idx] = c;
          pk[q] = (short)f2bf_fast(fsig(ov) * ftanh(c));
        }
        *(s16x4*)&A[no + (mt ? r1 : r0) + 64 + jbase] = pk;   // h1(t) -> nxt
      }
    }
    __syncthreads();   // B2: h1(t), x(t+1) visible; buffers swap
  };

  for (int tb = 0; tb < 382; tb += 2){
    phase(tb,     0,    ABUF);
    phase(tb + 1, ABUF, 0);
  }
  phase(382, 0, ABUF);     // t=382 (even): cur=buf0, h1(382)->buf1
  headOp(382, ABUF);       // final output row, after phase 382's B2
}

extern "C" void kernel_launch(void* const* d_in, const int* in_sizes, int n_in,
                              void* d_out, int out_size, void* d_ws, size_t ws_size,
                              hipStream_t stream) {
  (void)in_sizes; (void)n_in; (void)out_size; (void)d_ws; (void)ws_size;
  deepar_kernel<<<dim3(512), dim3(256), 0, stream>>>(
      (const float*)d_in[0],  (const float*)d_in[1],
      (const float*)d_in[2],  (const float*)d_in[3],
      (const float*)d_in[4],  (const float*)d_in[5],
      (const float*)d_in[6],  (const float*)d_in[7],
      (const float*)d_in[8],  (const float*)d_in[9],
      (const float*)d_in[10], (const float*)d_in[11],
      (const float*)d_in[12], (const float*)d_in[13],
      (float*)d_out);
}

// Round 4
// 1267.992 us; speedup vs baseline: 1.1474x; 1.0882x over previous
//
#include <hip/hip_runtime.h>

// DeepAR forward: B=32, L_IN=336, L_OUT=48, N=512, COV=4, EMB=32, H=64
// T = 383 steps, BN = 16384 sequences. 32 seqs/WG, 512 WGs, persistent, R2
// structure (layer-sequential, W1 in LDS, 3 barriers/step) kept verbatim —
// R3/R4/R5 showed any live-state increase spills (arch-VGPR cap 128) and
// occupancy/barriers are not the bottleneck (VALUBusy ~71% in all variants).
//
// R6: epilogue math rewrite (the measured VALU/trans consumer):
//  - per-gate log2e folded into weights/bias (i,f,o: *log2e; g: *2*log2e)
//    -> exp(-x) becomes bare v_exp_f32 (exp2), neg via input modifier.
//  - combined reciprocals: A=1+e^-f, B=1+e^-i, C=1+e^-2g, D=1+e^-o,
//    E=1+e^-2c':  c' = [c*BC + A*(2-C)]*rcp(A*BC);  h = (2-E)*rcp(D*E).
//  Per cell: 5 exp + 5 rcp + 5 mul  ->  5 exp + 2 rcp (+~2 VALU), ~30% of
//  the trans-pipe load removed. One fmin clamp guards exp2 overflow (c<<0).

#define T_STEPS 383
#define AST 168   // A row stride in shorts: [h0 0..63 | h1 64..127 | in 128..132 | pad]
#define LOG2E 1.44269504088896340736f

typedef __attribute__((ext_vector_type(8))) short short8;
typedef __attribute__((ext_vector_type(4))) float floatx4;

__device__ __forceinline__ unsigned short f2bf(float f){   // RNE (prologue)
  union { float f; unsigned u; } v; v.f = f;
  unsigned u = v.u + 0x7fffu + ((v.u >> 16) & 1u);
  return (unsigned short)(u >> 16);
}
__device__ __forceinline__ unsigned short f2bf_fast(float f){  // round-half-up, 2 instrs
  union { float f; unsigned u; } v; v.f = f;
  return (unsigned short)((v.u + 0x8000u) >> 16);
}
__device__ __forceinline__ float bf2f(unsigned short b){
  union { unsigned u; float f; } v; v.u = ((unsigned)b) << 16; return v.f;
}

// LSTM cell epilogue on log2e-prescaled pre-activations.
// iv,fv,ov = pre-act * log2e; gv = pre-act * 2*log2e. Updates c, returns h.
__device__ __forceinline__ float lstm_h(float iv, float fv, float gv, float ov, float& c){
  const float ea = __builtin_amdgcn_exp2f(-fv);   // e^-f
  const float eb = __builtin_amdgcn_exp2f(-iv);   // e^-i
  const float ec = __builtin_amdgcn_exp2f(-gv);   // e^-2g
  const float eo = __builtin_amdgcn_exp2f(-ov);   // e^-o
  const float A = 1.f + ea, B = 1.f + eb, C = 1.f + ec, D = 1.f + eo;
  const float BC = B * C;
  const float num = c * BC + A * (2.f - C);       // sig(f)c + sig(i)tanh(g), * A*BC
  const float cn = num * __builtin_amdgcn_rcpf(A * BC);
  c = cn;
  const float arg = fminf(cn * (-2.f * LOG2E), 126.f);   // clamp: c<<0 overflow guard
  const float E = 1.f + __builtin_amdgcn_exp2f(arg);     // 1 + e^-2c
  return (2.f - E) * __builtin_amdgcn_rcpf(D * E);       // sig(o)*tanh(c)
}

__global__ __launch_bounds__(256, 2) void deepar_kernel(
    const float* __restrict__ hist, const float* __restrict__ fut,
    const float* __restrict__ embW, const float* __restrict__ embB,
    const float* __restrict__ Wih0, const float* __restrict__ Whh0,
    const float* __restrict__ bih0, const float* __restrict__ bhh0,
    const float* __restrict__ Wih1, const float* __restrict__ Whh1,
    const float* __restrict__ bih1, const float* __restrict__ bhh1,
    const float* __restrict__ headW, const float* __restrict__ headB,
    float* __restrict__ outp)
{
  const int tid  = threadIdx.x;
  const int lane = tid & 63;
  const int wv   = tid >> 6;        // wave -> gate-column sub-block
  const int l15  = lane & 15;
  const int quad = lane >> 4;       // 0..3
  const int koff = quad * 8;
  const int jcol = wv * 16 + l15;   // hidden-unit index this lane owns

  const int b  = blockIdx.x >> 4;            // batch
  const int n0 = (blockIdx.x & 15) * 32;     // first series index

  __shared__ __align__(16) unsigned short A[32 * AST];
  __shared__ __align__(16) unsigned short W1[256 * 128];  // layer-1 B-frags, frag-ordered
  __shared__ float HW[128];

  for (int i = tid; i < 32 * AST; i += 256) A[i] = 0;
  if (tid < 128) HW[tid] = headW[tid];
  const float hb0 = headB[0], hb1 = headB[1];

  // ---- layer-0 weight B-fragments in registers; layer-1 frags -> LDS ----
  // B-frag (16x16x32): lane holds B^T[n=lane&15][k = quad*8 + j], j=0..7
  // All gate rows pre-scaled: i,f,o by log2e; g by 2*log2e (epilogue uses exp2).
  short8 bf0[4][3];   // [gate][kf]: kf0,1 = Whh0 (k 0..63); kf2 = input cols (k 128..159)
  float  bi0[4], bi1[4];
  #pragma unroll
  for (int g = 0; g < 4; ++g){
    const float gsc = (g == 2) ? 2.f * LOG2E : LOG2E;   // gate pre-act scale
    const int r = g * 64 + wv * 16 + l15;     // gate row 0..255
    float u = 0.f, bb = bih0[r] + bhh0[r];
    #pragma unroll
    for (int e = 0; e < 32; ++e){
      float wval = Wih0[r * 36 + e];
      u  += wval * embW[e];
      bb += wval * embB[e];
    }
    bi0[g] = bb * gsc;
    bi1[g] = (bih1[r] + bhh1[r]) * gsc;
    #pragma unroll
    for (int kf = 0; kf < 2; ++kf)
      #pragma unroll
      for (int j = 0; j < 8; ++j)
        bf0[g][kf][j] = (short)f2bf(Whh0[r * 64 + kf * 32 + koff + j] * gsc);
    #pragma unroll
    for (int j = 0; j < 8; ++j){
      int kk = koff + j;          // local k within input frag; col = 128+kk
      float v = 0.f;
      if (kk == 0) v = u;                               // prev -> u[r]
      else if (kk >= 1 && kk <= 4) v = Wih0[r * 36 + 32 + (kk - 1)];
      bf0[g][2][j] = (short)f2bf(v * gsc);
    }
    #pragma unroll
    for (int kf = 0; kf < 4; ++kf){
      const float* src = (kf < 2) ? (Wih1 + r * 64 + kf * 32)
                                  : (Whh1 + r * 64 + (kf - 2) * 32);
      short8 w;
      #pragma unroll
      for (int j = 0; j < 8; ++j)
        w[j] = (short)f2bf(src[koff + j] * gsc);
      // frag-ordered: wave wv's (g,kf) frag at contiguous 64x16B, lane-linear
      *(short8*)&W1[(((wv * 16 + g * 4 + kf) * 64) + lane) * 8] = w;
    }
  }

  // ---- input staging (prev: 32 threads; cov: 128 threads) ----
  const bool isPrev = (tid < 32);
  const bool isCov  = (tid >= 64 && tid < 192);
  int ss = 0, cc = 0;
  if (isPrev){ ss = tid; cc = 0; }
  if (isCov) { ss = (tid - 64) >> 2; cc = 1 + ((tid - 64) & 3); }
  const int myN = n0 + ss;

  auto loadSlab = [&](int tt) -> float {
    if (isPrev){
      int l = tt; if (l > 383) l = 383;
      return (l < 336) ? hist[(((size_t)b * 336 + l) * 512 + myN) * 5]
                       : fut [(((size_t)b * 48 + (l - 336)) * 512 + myN) * 5];
    } else if (isCov){
      int l = tt + 1; if (l > 383) l = 383;
      return (l < 336) ? hist[(((size_t)b * 336 + l) * 512 + myN) * 5 + cc]
                       : fut [(((size_t)b * 48 + (l - 336)) * 512 + myN) * 5 + cc];
    }
    return 0.f;
  };

  float rIn = loadSlab(0);
  if (isPrev || isCov) A[ss * AST + 128 + cc] = f2bf(rIn);
  rIn = loadSlab(1);   // prefetch step 1

  float c0s[8], c1s[8];
  #pragma unroll
  for (int i = 0; i < 8; ++i){ c0s[i] = 0.f; c1s[i] = 0.f; }

  __syncthreads();

  for (int t = 0; t < T_STEPS; ++t){
    // ================= layer 0 (K-frags at col 0,32,128) =================
    floatx4 acc[4][2];
    #pragma unroll
    for (int g = 0; g < 4; ++g)
      #pragma unroll
      for (int mt = 0; mt < 2; ++mt){
        floatx4 binit = { bi0[g], bi0[g], bi0[g], bi0[g] };
        acc[g][mt] = binit;
      }
    const int c0off[3] = { 0, 32, 128 };
    #pragma unroll
    for (int mt = 0; mt < 2; ++mt){
      #pragma unroll
      for (int kf = 0; kf < 3; ++kf){
        short8 af = *(const short8*)&A[(mt * 16 + l15) * AST + c0off[kf] + koff];
        #pragma unroll
        for (int g = 0; g < 4; ++g)
          acc[g][mt] = __builtin_amdgcn_mfma_f32_16x16x32_bf16(af, bf0[g][kf], acc[g][mt], 0, 0, 0);
      }
    }
    float hn[8];
    #pragma unroll
    for (int mt = 0; mt < 2; ++mt)
      #pragma unroll
      for (int q = 0; q < 4; ++q){
        int idx = mt * 4 + q;
        hn[idx] = lstm_h(acc[0][mt][q], acc[1][mt][q], acc[2][mt][q], acc[3][mt][q], c0s[idx]);
      }
    __syncthreads();   // B1: all layer-0 reads of A done
    #pragma unroll
    for (int mt = 0; mt < 2; ++mt)
      #pragma unroll
      for (int q = 0; q < 4; ++q){
        int s = mt * 16 + quad * 4 + q;
        A[s * AST + jcol] = f2bf_fast(hn[mt * 4 + q]);   // h0(t), single store
      }
    if (isPrev || isCov) A[ss * AST + 128 + cc] = f2bf_fast(rIn);  // inputs t+1
    rIn = loadSlab(t + 2);                                          // prefetch t+2
    __syncthreads();   // B2: h0 + inputs visible

    // ================= layer 1 (K = h0|h1, cols 0..127; W from LDS) ======
    #pragma unroll
    for (int g = 0; g < 4; ++g)
      #pragma unroll
      for (int mt = 0; mt < 2; ++mt){
        floatx4 binit = { bi1[g], bi1[g], bi1[g], bi1[g] };
        acc[g][mt] = binit;
      }
    #pragma unroll
    for (int kf = 0; kf < 4; ++kf){
      short8 wfr[4];
      #pragma unroll
      for (int g = 0; g < 4; ++g)
        wfr[g] = *(const short8*)&W1[(((wv * 16 + g * 4 + kf) * 64) + lane) * 8];
      #pragma unroll
      for (int mt = 0; mt < 2; ++mt){
        short8 af = *(const short8*)&A[(mt * 16 + l15) * AST + kf * 32 + koff];
        #pragma unroll
        for (int g = 0; g < 4; ++g)
          acc[g][mt] = __builtin_amdgcn_mfma_f32_16x16x32_bf16(af, wfr[g], acc[g][mt], 0, 0, 0);
      }
    }
    #pragma unroll
    for (int mt = 0; mt < 2; ++mt)
      #pragma unroll
      for (int q = 0; q < 4; ++q){
        int idx = mt * 4 + q;
        hn[idx] = lstm_h(acc[0][mt][q], acc[1][mt][q], acc[2][mt][q], acc[3][mt][q], c1s[idx]);
      }
    __syncthreads();   // B3: all layer-1 reads of h1(t-1) done
    #pragma unroll
    for (int mt = 0; mt < 2; ++mt)
      #pragma unroll
      for (int q = 0; q < 4; ++q){
        int s = mt * 16 + quad * 4 + q;
        A[s * AST + 64 + jcol] = f2bf_fast(hn[mt * 4 + q]);   // h1(t)
      }
    // next step's layer-0 reads cols 0..63/128..159 only — no barrier needed
    // until B1; h1 readers (next layer-1) are behind B1+B2.

    // ================= head (only last 48 steps produce output) =========
    if (t >= 335){
      __syncthreads();   // h1 visible for head reads
      const int hs = tid >> 3, outc = (tid >> 2) & 1, part = tid & 3;
      const short8 hv0 = *(const short8*)&A[hs * AST + 64 + part * 16];
      const short8 hv1 = *(const short8*)&A[hs * AST + 64 + part * 16 + 8];
      float p = 0.f;
      #pragma unroll
      for (int jj = 0; jj < 8; ++jj){
        float a0 = fmaxf(bf2f((unsigned short)hv0[jj]), 0.f);
        float a1 = fmaxf(bf2f((unsigned short)hv1[jj]), 0.f);
        p += a0 * HW[outc * 64 + part * 16 + jj];
        p += a1 * HW[outc * 64 + part * 16 + 8 + jj];
      }
      p += __shfl_xor(p, 1);
      p += __shfl_xor(p, 2);
      if ((tid & 3) == 0){
        float val;
        if (outc == 0) val = p + hb0;
        else {
          float x = p + hb1;   // softplus, stable
          val = fmaxf(x, 0.f) + __logf(1.f + __expf(-fabsf(x)));
        }
        outp[(((size_t)b * 48 + (t - 335)) * 512 + (n0 + hs)) * 2 + outc] = val;
      }
    }
  }
}

extern "C" void kernel_launch(void* const* d_in, const int* in_sizes, int n_in,
                              void* d_out, int out_size, void* d_ws, size_t ws_size,
                              hipStream_t stream) {
  (void)in_sizes; (void)n_in; (void)out_size; (void)d_ws; (void)ws_size;
  deepar_kernel<<<dim3(512), dim3(256), 0, stream>>>(
      (const float*)d_in[0],  (const float*)d_in[1],
      (const float*)d_in[2],  (const float*)d_in[3],
      (const float*)d_in[4],  (const float*)d_in[5],
      (const float*)d_in[6],  (const float*)d_in[7],
      (const float*)d_in[8],  (const float*)d_in[9],
      (const float*)d_in[10], (const float*)d_in[11],
      (const float*)d_in[12], (const float*)d_in[13],
      (float*)d_out);
}

// Round 6
// 1212.668 us; speedup vs baseline: 1.1997x; 1.0456x over previous
//
#include <hip/hip_runtime.h>

// DeepAR forward: B=32, L_IN=336, L_OUT=48, N=512, COV=4, EMB=32, H=64
// T = 383 steps, BN = 16384 sequences. 32 seqs/WG, 512 WGs, persistent.
//
// R7 = R6 (trans-reduced epilogue, W1 in LDS, 128-VGPR regime) + h1 ping-pong:
//  - A rows widened to AST=232: [h0 0..63 | h1_even 64..127 | x 128..132 |
//    h1_odd 144..207 | spare]. h1(t) is stored to region (t&1), read from
//    region ((t-1)&1): the B3 anti-dependency barrier disappears (t's h1
//    store and t+1's L1 reads are separated by t+1's B1+B2).
//  - head(t-1) moves into the B1-B2 window (reads the stable h1(t-1) region)
//    -> its 48 extra barriers also disappear. 2 barriers/step total.
//  - LDS 80896 B/WG (A 14848 + W1 65536 + HW 512): still 2 WGs/CU.
//  - AST=232 keeps dword-stride class (116 mod 32 = 20): same free 2-way
//    bank aliasing as AST=168; rows stay 16B-aligned for ds_read_b128.
//  - R3/R4/R5 lessons: never grow per-wave live state (alloc cap 128 VGPR
//    -> scratch); occupancy is not the lever; barriers/idle are.
// (R5 round: bench infra failed twice — resubmission, kernel unchanged;
//  barrier-uniformity + ping-pong + LDS-fit re-audited, no defect found.)

#define T_STEPS 383
#define AST 232
#define LOG2E 1.44269504088896340736f

typedef __attribute__((ext_vector_type(8))) short short8;
typedef __attribute__((ext_vector_type(4))) float floatx4;

__device__ __forceinline__ unsigned short f2bf(float f){   // RNE (prologue)
  union { float f; unsigned u; } v; v.f = f;
  unsigned u = v.u + 0x7fffu + ((v.u >> 16) & 1u);
  return (unsigned short)(u >> 16);
}
__device__ __forceinline__ unsigned short f2bf_fast(float f){  // round-half-up, 2 instrs
  union { float f; unsigned u; } v; v.f = f;
  return (unsigned short)((v.u + 0x8000u) >> 16);
}
__device__ __forceinline__ float bf2f(unsigned short b){
  union { unsigned u; float f; } v; v.u = ((unsigned)b) << 16; return v.f;
}

// LSTM cell epilogue on log2e-prescaled pre-activations.
// iv,fv,ov = pre-act * log2e; gv = pre-act * 2*log2e. Updates c, returns h.
__device__ __forceinline__ float lstm_h(float iv, float fv, float gv, float ov, float& c){
  const float ea = __builtin_amdgcn_exp2f(-fv);   // e^-f
  const float eb = __builtin_amdgcn_exp2f(-iv);   // e^-i
  const float ec = __builtin_amdgcn_exp2f(-gv);   // e^-2g
  const float eo = __builtin_amdgcn_exp2f(-ov);   // e^-o
  const float A = 1.f + ea, B = 1.f + eb, C = 1.f + ec, D = 1.f + eo;
  const float BC = B * C;
  const float num = c * BC + A * (2.f - C);       // sig(f)c + sig(i)tanh(g), * A*BC
  const float cn = num * __builtin_amdgcn_rcpf(A * BC);
  c = cn;
  const float arg = fminf(cn * (-2.f * LOG2E), 126.f);   // clamp: c<<0 overflow guard
  const float E = 1.f + __builtin_amdgcn_exp2f(arg);     // 1 + e^-2c
  return (2.f - E) * __builtin_amdgcn_rcpf(D * E);       // sig(o)*tanh(c)
}

__global__ __launch_bounds__(256, 2) void deepar_kernel(
    const float* __restrict__ hist, const float* __restrict__ fut,
    const float* __restrict__ embW, const float* __restrict__ embB,
    const float* __restrict__ Wih0, const float* __restrict__ Whh0,
    const float* __restrict__ bih0, const float* __restrict__ bhh0,
    const float* __restrict__ Wih1, const float* __restrict__ Whh1,
    const float* __restrict__ bih1, const float* __restrict__ bhh1,
    const float* __restrict__ headW, const float* __restrict__ headB,
    float* __restrict__ outp)
{
  const int tid  = threadIdx.x;
  const int lane = tid & 63;
  const int wv   = tid >> 6;        // wave -> gate-column sub-block
  const int l15  = lane & 15;
  const int quad = lane >> 4;       // 0..3
  const int koff = quad * 8;
  const int jcol = wv * 16 + l15;   // hidden-unit index this lane owns

  const int b  = blockIdx.x >> 4;            // batch
  const int n0 = (blockIdx.x & 15) * 32;     // first series index

  __shared__ __align__(16) unsigned short A[32 * AST];
  __shared__ __align__(16) unsigned short W1[256 * 128];  // layer-1 B-frags, frag-ordered
  __shared__ float HW[128];

  for (int i = tid; i < 32 * AST; i += 256) A[i] = 0;
  if (tid < 128) HW[tid] = headW[tid];
  const float hb0 = headB[0], hb1 = headB[1];

  // ---- layer-0 weight B-fragments in registers; layer-1 frags -> LDS ----
  // B-frag (16x16x32): lane holds B^T[n=lane&15][k = quad*8 + j], j=0..7
  // All gate rows pre-scaled: i,f,o by log2e; g by 2*log2e (epilogue uses exp2).
  short8 bf0[4][3];   // [gate][kf]: kf0,1 = Whh0 (k 0..63); kf2 = input cols (k 128..159)
  float  bi0[4], bi1[4];
  #pragma unroll
  for (int g = 0; g < 4; ++g){
    const float gsc = (g == 2) ? 2.f * LOG2E : LOG2E;   // gate pre-act scale
    const int r = g * 64 + wv * 16 + l15;     // gate row 0..255
    float u = 0.f, bb = bih0[r] + bhh0[r];
    #pragma unroll
    for (int e = 0; e < 32; ++e){
      float wval = Wih0[r * 36 + e];
      u  += wval * embW[e];
      bb += wval * embB[e];
    }
    bi0[g] = bb * gsc;
    bi1[g] = (bih1[r] + bhh1[r]) * gsc;
    #pragma unroll
    for (int kf = 0; kf < 2; ++kf)
      #pragma unroll
      for (int j = 0; j < 8; ++j)
        bf0[g][kf][j] = (short)f2bf(Whh0[r * 64 + kf * 32 + koff + j] * gsc);
    #pragma unroll
    for (int j = 0; j < 8; ++j){
      int kk = koff + j;          // local k within input frag; col = 128+kk
      float v = 0.f;
      if (kk == 0) v = u;                               // prev -> u[r]
      else if (kk >= 1 && kk <= 4) v = Wih0[r * 36 + 32 + (kk - 1)];
      bf0[g][2][j] = (short)f2bf(v * gsc);
    }
    #pragma unroll
    for (int kf = 0; kf < 4; ++kf){
      const float* src = (kf < 2) ? (Wih1 + r * 64 + kf * 32)
                                  : (Whh1 + r * 64 + (kf - 2) * 32);
      short8 w;
      #pragma unroll
      for (int j = 0; j < 8; ++j)
        w[j] = (short)f2bf(src[koff + j] * gsc);
      // frag-ordered: wave wv's (g,kf) frag at contiguous 64x16B, lane-linear
      *(short8*)&W1[(((wv * 16 + g * 4 + kf) * 64) + lane) * 8] = w;
    }
  }

  // ---- input staging (prev: 32 threads; cov: 128 threads) ----
  const bool isPrev = (tid < 32);
  const bool isCov  = (tid >= 64 && tid < 192);
  int ss = 0, cc = 0;
  if (isPrev){ ss = tid; cc = 0; }
  if (isCov) { ss = (tid - 64) >> 2; cc = 1 + ((tid - 64) & 3); }
  const int myN = n0 + ss;

  auto loadSlab = [&](int tt) -> float {
    if (isPrev){
      int l = tt; if (l > 383) l = 383;
      return (l < 336) ? hist[(((size_t)b * 336 + l) * 512 + myN) * 5]
                       : fut [(((size_t)b * 48 + (l - 336)) * 512 + myN) * 5];
    } else if (isCov){
      int l = tt + 1; if (l > 383) l = 383;
      return (l < 336) ? hist[(((size_t)b * 336 + l) * 512 + myN) * 5 + cc]
                       : fut [(((size_t)b * 48 + (l - 336)) * 512 + myN) * 5 + cc];
    }
    return 0.f;
  };

  float rIn = loadSlab(0);
  if (isPrev || isCov) A[ss * AST + 128 + cc] = f2bf(rIn);
  rIn = loadSlab(1);   // prefetch step 1

  float c0s[8], c1s[8];
  #pragma unroll
  for (int i = 0; i < 8; ++i){ c0s[i] = 0.f; c1s[i] = 0.f; }

  // head decomposition (fixed per thread)
  const int hd_hs   = tid >> 3;
  const int hd_outc = (tid >> 2) & 1;
  const int hd_part = tid & 3;

  auto headOp = [&](int tt, int reg){   // reads h1(tt) from region base `reg`
    const short8 hv0 = *(const short8*)&A[hd_hs * AST + reg + hd_part * 16];
    const short8 hv1 = *(const short8*)&A[hd_hs * AST + reg + hd_part * 16 + 8];
    float p = 0.f;
    #pragma unroll
    for (int jj = 0; jj < 8; ++jj){
      float a0 = fmaxf(bf2f((unsigned short)hv0[jj]), 0.f);
      float a1 = fmaxf(bf2f((unsigned short)hv1[jj]), 0.f);
      p += a0 * HW[hd_outc * 64 + hd_part * 16 + jj];
      p += a1 * HW[hd_outc * 64 + hd_part * 16 + 8 + jj];
    }
    p += __shfl_xor(p, 1);
    p += __shfl_xor(p, 2);
    if ((tid & 3) == 0){
      float val;
      if (hd_outc == 0) val = p + hb0;
      else {
        float x = p + hb1;   // softplus, stable
        val = fmaxf(x, 0.f) + __logf(1.f + __expf(-fabsf(x)));
      }
      outp[(((size_t)b * 48 + (tt - 335)) * 512 + (n0 + hd_hs)) * 2 + hd_outc] = val;
    }
  };

  __syncthreads();

  for (int t = 0; t < T_STEPS; ++t){
    const int h1rd = (t & 1) ? 64 : 144;   // h1(t-1) region  ((t-1)&1)
    const int h1wr = (t & 1) ? 144 : 64;   // h1(t)   region  (t&1)

    // ================= layer 0 (K-frags at col 0,32,128) =================
    floatx4 acc[4][2];
    #pragma unroll
    for (int g = 0; g < 4; ++g)
      #pragma unroll
      for (int mt = 0; mt < 2; ++mt){
        floatx4 binit = { bi0[g], bi0[g], bi0[g], bi0[g] };
        acc[g][mt] = binit;
      }
    const int c0off[3] = { 0, 32, 128 };
    #pragma unroll
    for (int mt = 0; mt < 2; ++mt){
      #pragma unroll
      for (int kf = 0; kf < 3; ++kf){
        short8 af = *(const short8*)&A[(mt * 16 + l15) * AST + c0off[kf] + koff];
        #pragma unroll
        for (int g = 0; g < 4; ++g)
          acc[g][mt] = __builtin_amdgcn_mfma_f32_16x16x32_bf16(af, bf0[g][kf], acc[g][mt], 0, 0, 0);
      }
    }
    float hn[8];
    #pragma unroll
    for (int mt = 0; mt < 2; ++mt)
      #pragma unroll
      for (int q = 0; q < 4; ++q){
        int idx = mt * 4 + q;
        hn[idx] = lstm_h(acc[0][mt][q], acc[1][mt][q], acc[2][mt][q], acc[3][mt][q], c0s[idx]);
      }
    __syncthreads();   // B1: all layer-0 reads of A done
    #pragma unroll
    for (int mt = 0; mt < 2; ++mt)
      #pragma unroll
      for (int q = 0; q < 4; ++q){
        int s = mt * 16 + quad * 4 + q;
        A[s * AST + jcol] = f2bf_fast(hn[mt * 4 + q]);   // h0(t), single store
      }
    if (isPrev || isCov) A[ss * AST + 128 + cc] = f2bf_fast(rIn);  // inputs t+1
    rIn = loadSlab(t + 2);                                          // prefetch t+2
    // head(t-1): reads h1(t-1) region — stable this step (t's h1 store goes
    // to the other region; next overwrite of h1rd is t+1's L1, after 2 bars).
    if (t >= 336) headOp(t - 1, h1rd);
    __syncthreads();   // B2: h0 + inputs visible

    // ================= layer 1 (K = h0 | h1(t-1), W from LDS) ============
    #pragma unroll
    for (int g = 0; g < 4; ++g)
      #pragma unroll
      for (int mt = 0; mt < 2; ++mt){
        floatx4 binit = { bi1[g], bi1[g], bi1[g], bi1[g] };
        acc[g][mt] = binit;
      }
    const int c1off[4] = { 0, 32, h1rd, h1rd + 32 };
    #pragma unroll
    for (int kf = 0; kf < 4; ++kf){
      short8 wfr[4];
      #pragma unroll
      for (int g = 0; g < 4; ++g)
        wfr[g] = *(const short8*)&W1[(((wv * 16 + g * 4 + kf) * 64) + lane) * 8];
      #pragma unroll
      for (int mt = 0; mt < 2; ++mt){
        short8 af = *(const short8*)&A[(mt * 16 + l15) * AST + c1off[kf] + koff];
        #pragma unroll
        for (int g = 0; g < 4; ++g)
          acc[g][mt] = __builtin_amdgcn_mfma_f32_16x16x32_bf16(af, wfr[g], acc[g][mt], 0, 0, 0);
      }
    }
    #pragma unroll
    for (int mt = 0; mt < 2; ++mt)
      #pragma unroll
      for (int q = 0; q < 4; ++q){
        int idx = mt * 4 + q;
        hn[idx] = lstm_h(acc[0][mt][q], acc[1][mt][q], acc[2][mt][q], acc[3][mt][q], c1s[idx]);
      }
    // h1(t) -> ping-pong region: no barrier needed (readers are 2 bars away)
    #pragma unroll
    for (int mt = 0; mt < 2; ++mt)
      #pragma unroll
      for (int q = 0; q < 4; ++q){
        int s = mt * 16 + quad * 4 + q;
        A[s * AST + h1wr + jcol] = f2bf_fast(hn[mt * 4 + q]);   // h1(t)
      }
  }

  // final output row: h1(382) in region 382&1 = 0 -> base 64
  __syncthreads();
  headOp(382, 64);
}

extern "C" void kernel_launch(void* const* d_in, const int* in_sizes, int n_in,
                              void* d_out, int out_size, void* d_ws, size_t ws_size,
                              hipStream_t stream) {
  (void)in_sizes; (void)n_in; (void)out_size; (void)d_ws; (void)ws_size;
  deepar_kernel<<<dim3(512), dim3(256), 0, stream>>>(
      (const float*)d_in[0],  (const float*)d_in[1],
      (const float*)d_in[2],  (const float*)d_in[3],
      (const float*)d_in[4],  (const float*)d_in[5],
      (const float*)d_in[6],  (const float*)d_in[7],
      (const float*)d_in[8],  (const float*)d_in[9],
      (const float*)d_in[10], (const float*)d_in[11],
      (const float*)d_in[12], (const float*)d_in[13],
      (float*)d_out);
}

// Round 7
// 1193.768 us; speedup vs baseline: 1.2187x; 1.0158x over previous
//
#include <hip/hip_runtime.h>

// DeepAR forward: B=32, L_IN=336, L_OUT=48, N=512, COV=4, EMB=32, H=64
// T = 383 steps, BN = 16384 sequences. 32 seqs/WG, 512 WGs, persistent.
//
// R8 = R7 (2-barrier ping-pong, trans-reduced epilogue, 128-VGPR regime) +
//  1) L0 operand swap (A=W, B=x): lane owns 4 consecutive hidden units ->
//     h0 store = 2 ds_write_b64 (2-way/free) + 4 v_cvt_pk_bf16_f32,
//     replacing 8 conflicting ds_write_b16 + 16 f2bf VALU. L0 bias rides
//     the matmul via constant-1.0 cols 133/134 (R3-verified; -4 regs).
//     L1 stays unswapped (scalar bi1[g] — no register growth).
//  2) Barrier diet: B1 = bare s_barrier (L0's reads are drained by use;
//     h1(t-1) writes are covered by B2's lgkmcnt). B2 = lgkmcnt(0)+barrier.
//     No vmcnt(0) drain anywhere in the loop; the x prefetch is issued at
//     the TOP of the step so its latency hides under the whole L0 phase.
//  3) Anti-phase stagger: WGs with (blockIdx>>3)&1 delay ~2-3k cycles at
//     startup so co-resident WGs interleave epilogue (trans-pipe) and MFMA
//     phases instead of colliding (m114: pipes co-schedule across waves).
//  R3/R4/R5 lessons: never grow per-wave live state (alloc cap 128 VGPR).

#define T_STEPS 383
#define AST 232
#define LOG2E 1.44269504088896340736f

typedef __attribute__((ext_vector_type(8))) short short8;
typedef __attribute__((ext_vector_type(2))) unsigned int uint2v;
typedef __attribute__((ext_vector_type(4))) float floatx4;

__device__ __forceinline__ unsigned short f2bf(float f){   // RNE (prologue)
  union { float f; unsigned u; } v; v.f = f;
  unsigned u = v.u + 0x7fffu + ((v.u >> 16) & 1u);
  return (unsigned short)(u >> 16);
}
__device__ __forceinline__ unsigned short f2bf_fast(float f){  // round-half-up, 2 instrs
  union { float f; unsigned u; } v; v.f = f;
  return (unsigned short)((v.u + 0x8000u) >> 16);
}
__device__ __forceinline__ float bf2f(unsigned short b){
  union { unsigned u; float f; } v; v.u = ((unsigned)b) << 16; return v.f;
}

// LSTM cell epilogue on log2e-prescaled pre-activations.
// iv,fv,ov = pre-act * log2e; gv = pre-act * 2*log2e. Updates c, returns h.
__device__ __forceinline__ float lstm_h(float iv, float fv, float gv, float ov, float& c){
  const float ea = __builtin_amdgcn_exp2f(-fv);   // e^-f
  const float eb = __builtin_amdgcn_exp2f(-iv);   // e^-i
  const float ec = __builtin_amdgcn_exp2f(-gv);   // e^-2g
  const float eo = __builtin_amdgcn_exp2f(-ov);   // e^-o
  const float A = 1.f + ea, B = 1.f + eb, C = 1.f + ec, D = 1.f + eo;
  const float BC = B * C;
  const float num = c * BC + A * (2.f - C);       // sig(f)c + sig(i)tanh(g), * A*BC
  const float cn = num * __builtin_amdgcn_rcpf(A * BC);
  c = cn;
  const float arg = fminf(cn * (-2.f * LOG2E), 126.f);   // clamp: c<<0 overflow guard
  const float E = 1.f + __builtin_amdgcn_exp2f(arg);     // 1 + e^-2c
  return (2.f - E) * __builtin_amdgcn_rcpf(D * E);       // sig(o)*tanh(c)
}

__global__ __launch_bounds__(256, 2) void deepar_kernel(
    const float* __restrict__ hist, const float* __restrict__ fut,
    const float* __restrict__ embW, const float* __restrict__ embB,
    const float* __restrict__ Wih0, const float* __restrict__ Whh0,
    const float* __restrict__ bih0, const float* __restrict__ bhh0,
    const float* __restrict__ Wih1, const float* __restrict__ Whh1,
    const float* __restrict__ bih1, const float* __restrict__ bhh1,
    const float* __restrict__ headW, const float* __restrict__ headB,
    float* __restrict__ outp)
{
  const int tid  = threadIdx.x;
  const int lane = tid & 63;
  const int wv   = tid >> 6;        // wave -> gate-column sub-block (jt)
  const int l15  = lane & 15;
  const int quad = lane >> 4;       // 0..3
  const int koff = quad * 8;
  const int jcol  = wv * 16 + l15;        // L1: hidden-unit col this lane owns
  const int jbase = wv * 16 + quad * 4;   // L0 swapped: first of 4 hidden units

  const int b  = blockIdx.x >> 4;            // batch
  const int n0 = (blockIdx.x & 15) * 32;     // first series index

  __shared__ __align__(16) unsigned short A[32 * AST];
  __shared__ __align__(16) unsigned short W1[256 * 128];  // layer-1 B-frags, frag-ordered
  __shared__ float HW[128];

  for (int i = tid; i < 32 * AST; i += 256) A[i] = 0;
  if (tid < 128) HW[tid] = headW[tid];
  __syncthreads();          // zero-fill visible before 1.0-cols + staging
  if (tid < 32){
    A[tid * AST + 133] = 0x3f80;   // 1.0 (L0 bias-hi column)
    A[tid * AST + 134] = 0x3f80;   // 1.0 (L0 bias-residual column)
  }
  const float hb0 = headB[0], hb1 = headB[1];

  // ---- layer-0 weight A-frags in registers; layer-1 B-frags -> LDS ----
  // frag (16x16x32): lane holds elem (idx=lane&15, k=quad*8+j), j=0..7 —
  // identical lane map for A- and B-roles, so bf0 content is unchanged.
  // All gate rows pre-scaled: i,f,o by log2e; g by 2*log2e (exp2 epilogue).
  short8 bf0[4][3];   // [gate][kf]: kf0,1 = Whh0 (k 0..63); kf2 = input cols (k 128..159)
  float  bi1[4];
  #pragma unroll
  for (int g = 0; g < 4; ++g){
    const float gsc = (g == 2) ? 2.f * LOG2E : LOG2E;   // gate pre-act scale
    const int r = g * 64 + wv * 16 + l15;     // gate row 0..255
    float u = 0.f, bb = bih0[r] + bhh0[r];
    #pragma unroll
    for (int e = 0; e < 32; ++e){
      float wval = Wih0[r * 36 + e];
      u  += wval * embW[e];
      bb += wval * embB[e];
    }
    const float bbs = bb * gsc;
    const unsigned short bbq = f2bf(bbs);        // bias hi (bf16)
    const float bbr = bbs - bf2f(bbq);           // bias residual
    bi1[g] = (bih1[r] + bhh1[r]) * gsc;
    #pragma unroll
    for (int kf = 0; kf < 2; ++kf)
      #pragma unroll
      for (int j = 0; j < 8; ++j)
        bf0[g][kf][j] = (short)f2bf(Whh0[r * 64 + kf * 32 + koff + j] * gsc);
    #pragma unroll
    for (int j = 0; j < 8; ++j){
      int kk = koff + j;          // local k within input frag; col = 128+kk
      unsigned short q16;
      if (kk == 5)      q16 = bbq;                               // * 1.0 col
      else if (kk == 6) q16 = f2bf(bbr);                         // * 1.0 col
      else {
        float v = 0.f;
        if (kk == 0) v = u;                                      // prev -> u[r]
        else if (kk >= 1 && kk <= 4) v = Wih0[r * 36 + 32 + (kk - 1)];
        q16 = f2bf(v * gsc);
      }
      bf0[g][2][j] = (short)q16;
    }
    #pragma unroll
    for (int kf = 0; kf < 4; ++kf){
      const float* src = (kf < 2) ? (Wih1 + r * 64 + kf * 32)
                                  : (Whh1 + r * 64 + (kf - 2) * 32);
      short8 w;
      #pragma unroll
      for (int j = 0; j < 8; ++j)
        w[j] = (short)f2bf(src[koff + j] * gsc);
      *(short8*)&W1[(((wv * 16 + g * 4 + kf) * 64) + lane) * 8] = w;
    }
  }

  // ---- input staging (prev: 32 threads; cov: 128 threads) ----
  const bool isPrev = (tid < 32);
  const bool isCov  = (tid >= 64 && tid < 192);
  int ss = 0, cc = 0;
  if (isPrev){ ss = tid; cc = 0; }
  if (isCov) { ss = (tid - 64) >> 2; cc = 1 + ((tid - 64) & 3); }
  const int myN = n0 + ss;

  auto loadSlab = [&](int tt) -> float {
    if (isPrev){
      int l = tt; if (l > 383) l = 383;
      return (l < 336) ? hist[(((size_t)b * 336 + l) * 512 + myN) * 5]
                       : fut [(((size_t)b * 48 + (l - 336)) * 512 + myN) * 5];
    } else if (isCov){
      int l = tt + 1; if (l > 383) l = 383;
      return (l < 336) ? hist[(((size_t)b * 336 + l) * 512 + myN) * 5 + cc]
                       : fut [(((size_t)b * 48 + (l - 336)) * 512 + myN) * 5 + cc];
    }
    return 0.f;
  };

  float rCur = loadSlab(0);
  if (isPrev || isCov) A[ss * AST + 128 + cc] = f2bf(rCur);
  rCur = loadSlab(1);   // holds x(t+1) entering each step

  float c0s[8], c1s[8];
  #pragma unroll
  for (int i = 0; i < 8; ++i){ c0s[i] = 0.f; c1s[i] = 0.f; }

  // head decomposition (fixed per thread)
  const int hd_hs   = tid >> 3;
  const int hd_outc = (tid >> 2) & 1;
  const int hd_part = tid & 3;

  auto headOp = [&](int tt, int reg){   // reads h1(tt) from region base `reg`
    const short8 hv0 = *(const short8*)&A[hd_hs * AST + reg + hd_part * 16];
    const short8 hv1 = *(const short8*)&A[hd_hs * AST + reg + hd_part * 16 + 8];
    float p = 0.f;
    #pragma unroll
    for (int jj = 0; jj < 8; ++jj){
      float a0 = fmaxf(bf2f((unsigned short)hv0[jj]), 0.f);
      float a1 = fmaxf(bf2f((unsigned short)hv1[jj]), 0.f);
      p += a0 * HW[hd_outc * 64 + hd_part * 16 + jj];
      p += a1 * HW[hd_outc * 64 + hd_part * 16 + 8 + jj];
    }
    p += __shfl_xor(p, 1);
    p += __shfl_xor(p, 2);
    if ((tid & 3) == 0){
      float val;
      if (hd_outc == 0) val = p + hb0;
      else {
        float x = p + hb1;   // softplus, stable
        val = fmaxf(x, 0.f) + __logf(1.f + __expf(-fabsf(x)));
      }
      outp[(((size_t)b * 48 + (tt - 335)) * 512 + (n0 + hd_hs)) * 2 + hd_outc] = val;
    }
  };

  // ---- anti-phase stagger: offset half the WGs by ~2-3k cycles so the two
  // co-resident WGs per CU interleave trans-heavy and MFMA-heavy phases.
  // (bit 3: under 8-XCD round-robin, co-resident WGs differ by 8.)
  if (((blockIdx.x >> 3) & 1) && wv == 0){
    float z = 1.5f + (float)lane;
    for (int i = 0; i < 300; ++i)
      asm volatile("v_exp_f32 %0, %1" : "=v"(z) : "v"(z));   // dependent chain
    (void)z;
  }

  __syncthreads();

  for (int t = 0; t < T_STEPS; ++t){
    const int h1rd = (t & 1) ? 64 : 144;   // h1(t-1) region  ((t-1)&1)
    const int h1wr = (t & 1) ? 144 : 64;   // h1(t)   region  (t&1)

    const float rNxt = loadSlab(t + 2);    // issue global load at step top

    // ======= layer 0: swapped operands (A = W frags, B = x frags) ========
    floatx4 acc[4][2];
    #pragma unroll
    for (int g = 0; g < 4; ++g)
      #pragma unroll
      for (int mt = 0; mt < 2; ++mt){
        floatx4 z = {0.f, 0.f, 0.f, 0.f};   // bias rides cols 133/134
        acc[g][mt] = z;
      }
    const int c0off[3] = { 0, 32, 128 };
    #pragma unroll
    for (int mt = 0; mt < 2; ++mt){
      #pragma unroll
      for (int kf = 0; kf < 3; ++kf){
        short8 af = *(const short8*)&A[(mt * 16 + l15) * AST + c0off[kf] + koff];
        #pragma unroll
        for (int g = 0; g < 4; ++g)
          acc[g][mt] = __builtin_amdgcn_mfma_f32_16x16x32_bf16(bf0[g][kf], af, acc[g][mt], 0, 0, 0);
      }
    }
    // D layout (swapped): col = l15 = seq (mt*16+l15); row = quad*4+q =
    // hidden unit jbase+q. Lane cell (mt,q): seq mt*16+l15, hidden jbase+q.
    float hn[8];
    #pragma unroll
    for (int mt = 0; mt < 2; ++mt)
      #pragma unroll
      for (int q = 0; q < 4; ++q){
        int idx = mt * 4 + q;
        hn[idx] = lstm_h(acc[0][mt][q], acc[1][mt][q], acc[2][mt][q], acc[3][mt][q], c0s[idx]);
      }
    // B1: bare barrier. L0's reads are drained by their MFMA use; h1(t-1)
    // stores from last step are drained by B2's lgkmcnt before any reader.
    asm volatile("s_barrier" ::: "memory");
    // h0(t): 4 consecutive hidden units per lane -> cvt_pk + single b64
    #pragma unroll
    for (int mt = 0; mt < 2; ++mt){
      uint2v pk;
      asm("v_cvt_pk_bf16_f32 %0, %1, %2" : "=v"(pk.x) : "v"(hn[mt*4+0]), "v"(hn[mt*4+1]));
      asm("v_cvt_pk_bf16_f32 %0, %1, %2" : "=v"(pk.y) : "v"(hn[mt*4+2]), "v"(hn[mt*4+3]));
      *(uint2v*)&A[(mt * 16 + l15) * AST + jbase] = pk;
    }
    if (isPrev || isCov) A[ss * AST + 128 + cc] = f2bf_fast(rCur);  // x(t+1)
    // head(t-1): h1rd region stable this step (t's h1 goes to other region)
    if (t >= 336) headOp(t - 1, h1rd);
    rCur = rNxt;   // vmcnt wait lands here — load issued a full phase ago
    // B2: h0 + x stores must be visible -> lgkmcnt(0); no vmcnt drain.
    asm volatile("s_waitcnt lgkmcnt(0)\n\ts_barrier" ::: "memory");

    // ================= layer 1 (unswapped; K = h0 | h1(t-1)) =============
    #pragma unroll
    for (int g = 0; g < 4; ++g)
      #pragma unroll
      for (int mt = 0; mt < 2; ++mt){
        floatx4 binit = { bi1[g], bi1[g], bi1[g], bi1[g] };
        acc[g][mt] = binit;
      }
    const int c1off[4] = { 0, 32, h1rd, h1rd + 32 };
    #pragma unroll
    for (int kf = 0; kf < 4; ++kf){
      short8 wfr[4];
      #pragma unroll
      for (int g = 0; g < 4; ++g)
        wfr[g] = *(const short8*)&W1[(((wv * 16 + g * 4 + kf) * 64) + lane) * 8];
      #pragma unroll
      for (int mt = 0; mt < 2; ++mt){
        short8 af = *(const short8*)&A[(mt * 16 + l15) * AST + c1off[kf] + koff];
        #pragma unroll
        for (int g = 0; g < 4; ++g)
          acc[g][mt] = __builtin_amdgcn_mfma_f32_16x16x32_bf16(af, wfr[g], acc[g][mt], 0, 0, 0);
      }
    }
    #pragma unroll
    for (int mt = 0; mt < 2; ++mt)
      #pragma unroll
      for (int q = 0; q < 4; ++q){
        int idx = mt * 4 + q;
        hn[idx] = lstm_h(acc[0][mt][q], acc[1][mt][q], acc[2][mt][q], acc[3][mt][q], c1s[idx]);
      }
    // h1(t) -> ping-pong region: readers are 2 barriers away; store drains
    // at next step's B2 lgkmcnt before any reader touches it.
    #pragma unroll
    for (int mt = 0; mt < 2; ++mt)
      #pragma unroll
      for (int q = 0; q < 4; ++q){
        int s = mt * 16 + quad * 4 + q;
        A[s * AST + h1wr + jcol] = f2bf_fast(hn[mt * 4 + q]);   // h1(t)
      }
  }

  // final output row: h1(382) in region 382&1 = 0 -> base 64
  __syncthreads();
  headOp(382, 64);
}

extern "C" void kernel_launch(void* const* d_in, const int* in_sizes, int n_in,
                              void* d_out, int out_size, void* d_ws, size_t ws_size,
                              hipStream_t stream) {
  (void)in_sizes; (void)n_in; (void)out_size; (void)d_ws; (void)ws_size;
  deepar_kernel<<<dim3(512), dim3(256), 0, stream>>>(
      (const float*)d_in[0],  (const float*)d_in[1],
      (const float*)d_in[2],  (const float*)d_in[3],
      (const float*)d_in[4],  (const float*)d_in[5],
      (const float*)d_in[6],  (const float*)d_in[7],
      (const float*)d_in[8],  (const float*)d_in[9],
      (const float*)d_in[10], (const float*)d_in[11],
      (const float*)d_in[12], (const float*)d_in[13],
      (float*)d_out);
}